// Round 4
// baseline (58.575 us; speedup 1.0000x reference)
//
#include <hip/hip_runtime.h>

#define NN 16
#define NO 32
#define XCOLS 133

typedef _Float16 h2 __attribute__((ext_vector_type(2)));

static __device__ __forceinline__ h2 pk(float a, float b) {
    return __builtin_bit_cast(h2, __builtin_amdgcn_cvt_pkrtz(a, b));
}
static __device__ __forceinline__ float dot2(h2 a, h2 b, float c) {
    return __builtin_amdgcn_fdot2(a, b, c, false);
}
static __device__ __forceinline__ unsigned h2u(h2 v) {
    return __builtin_bit_cast(unsigned, v);
}
static __device__ __forceinline__ h2 u2h(unsigned v) {
    return __builtin_bit_cast(h2, v);
}

// packed-weight layout in d_ws (dword offsets); pairs along the contraction dim
#define OFF_PNW1 0     // [2][64]
#define OFF_PNW2 128   // [32][16]
#define OFF_RNW1 640   // [8][64]
#define OFF_RNW2 1152  // [32][8]
#define OFF_POW1 1408  // [1][64]
#define OFF_POW2 1472  // [32][16]
#define OFF_ROW1 1984  // [8][64]
#define OFF_ROW2 2496  // [32][8]
#define OFF_PSW1 2752  // [9][64]
#define OFF_PSW2 3328  // [32][64]
#define OFF_PSW3 5376  // [32][2]

__global__ void prep_weights(
    const float* __restrict__ pnW1, const float* __restrict__ pnW2,
    const float* __restrict__ rnW1, const float* __restrict__ rnW2,
    const float* __restrict__ poW1, const float* __restrict__ poW2,
    const float* __restrict__ roW1, const float* __restrict__ roW2,
    const float* __restrict__ psW1, const float* __restrict__ psW2,
    const float* __restrict__ psW3, unsigned* __restrict__ ws)
{
    const float* ins[11]  = {pnW1, pnW2, rnW1, rnW2, poW1, poW2, roW1, roW2, psW1, psW2, psW3};
    const int offs[11]    = {OFF_PNW1, OFF_PNW2, OFF_RNW1, OFF_RNW2, OFF_POW1, OFF_POW2,
                             OFF_ROW1, OFF_ROW2, OFF_PSW1, OFF_PSW2, OFF_PSW3};
    const int pairsv[11]  = {2, 32, 8, 32, 1, 32, 8, 32, 9, 32, 32};
    const int colsv[11]   = {64, 16, 64, 8, 64, 16, 64, 8, 64, 64, 2};
    for (int a = 0; a < 11; ++a) {
        const float* in = ins[a];
        const int C = colsv[a], n = pairsv[a] * C, off = offs[a];
        for (int i = threadIdx.x; i < n; i += blockDim.x) {
            const int p = i / C, c = i - p * C;
            ws[off + i] = h2u(pk(in[(2 * p) * C + c], in[(2 * p + 1) * C + c]));
        }
    }
}

// xs swizzle: pair-column cp in [0,32), element e in [0,64)
#define XS(cp, e) ((cp) * 64 + ((e) ^ (cp)))

__global__ __launch_bounds__(256, 5) void barrier_net_kernel(
    const float* __restrict__ x, const float* __restrict__ noise,
    const float* __restrict__ pnb1, const float* __restrict__ pnb2,
    const float* __restrict__ rnb1, const float* __restrict__ rnb2,
    const float* __restrict__ pob1, const float* __restrict__ pob2,
    const float* __restrict__ rob1, const float* __restrict__ rob2,
    const float* __restrict__ psb1, const float* __restrict__ psb2,
    const float* __restrict__ psb3,
    const unsigned* __restrict__ wsu,
    float* __restrict__ out)
{
    __shared__ unsigned xs_h[32 * 64];   // 8 KB: f16-pair staged point data
    __shared__ float4 bufA[16][64];      // 16 KB
    __shared__ float4 bufB[8][64];       // 8 KB   -> total 32 KB = 5 blocks/CU

    const int tid = threadIdx.x;
    const int l   = tid & 63;
    const int w   = __builtin_amdgcn_readfirstlane(tid >> 6);
    const int fb  = w * 16;
    const int e0  = blockIdx.x * 64;

    const float g0 = x[(size_t)(e0 + l) * XCOLS + 1];
    const float g1 = x[(size_t)(e0 + l) * XCOLS + 2];
    const float* __restrict__ src = x + (size_t)e0 * XCOLS;

    // ---- stage neighbor block cols [5,69) as f16 pairs
    #pragma unroll
    for (int it = 0; it < 8; ++it) {
        const int idx = it * 256 + tid;       // 0..2047
        const int ee  = idx >> 5;
        const int cp  = idx & 31;
        const float* p = src + (size_t)ee * XCOLS + 5 + 2 * cp;
        xs_h[XS(cp, ee)] = h2u(pk(p[0], p[1]));
    }
    __syncthreads();  // B1

    float bar0 = 0.f, bar1 = 0.f;

    // ================= Phase 1: neighbor L1 slice + pn partial =================
    float sn[16];
    #pragma unroll
    for (int f = 0; f < 16; ++f) sn[f] = 0.f;

    for (int j = 0; j < NN; ++j) {
        const h2 h01 = u2h(xs_h[XS(2 * j, l)]);
        const h2 h23 = u2h(xs_h[XS(2 * j + 1, l)]);
        #pragma unroll
        for (int f = 0; f < 16; ++f) {
            float t = dot2(h01, u2h(wsu[OFF_PNW1 + 0 * 64 + fb + f]), pnb1[fb + f]);
            t = dot2(h23, u2h(wsu[OFF_PNW1 + 1 * 64 + fb + f]), t);
            sn[f] += fmaxf(t, 0.f);
        }
    }
    // neighbor barrier partials: wave handles j in [4w,4w+4)
    #pragma unroll
    for (int jj = 0; jj < 4; ++jj) {
        const int j = 4 * w + jj;
        const h2 h01 = u2h(xs_h[XS(2 * j, l)]);
        const float v0 = (float)h01[0], v1 = (float)h01[1];
        const float nrm = sqrtf(v0 * v0 + v1 * v1);
        const float cc  = 0.01f * __builtin_amdgcn_rcpf(nrm * (nrm - 0.3f));
        bar0 -= cc * v0;
        bar1 -= cc * v1;
    }
    {
        h2 snp[8];
        #pragma unroll
        for (int i = 0; i < 8; ++i) snp[i] = pk(sn[2 * i], sn[2 * i + 1]);
        float pn[16];
        #pragma unroll
        for (int q = 0; q < 16; ++q) pn[q] = 0.f;
        #pragma unroll
        for (int p = 0; p < 8; ++p) {
            #pragma unroll
            for (int q = 0; q < 16; ++q)
                pn[q] = dot2(snp[p], u2h(wsu[OFF_PNW2 + (8 * w + p) * 16 + q]), pn[q]);
        }
        #pragma unroll
        for (int qc = 0; qc < 4; ++qc)
            bufA[w * 4 + qc][l] = make_float4(pn[qc*4+0], pn[qc*4+1], pn[qc*4+2], pn[qc*4+3]);
    }
    __syncthreads();  // B2

    // ================= Phase 2: rn partial; stage obstacle block ===============
    {
        float pn[16];
        #pragma unroll
        for (int q = 0; q < 16; ++q) pn[q] = 16.f * pnb2[q];
        #pragma unroll
        for (int w2 = 0; w2 < 4; ++w2) {
            #pragma unroll
            for (int qc = 0; qc < 4; ++qc) {
                const float4 v = bufA[w2 * 4 + qc][l];
                pn[qc*4+0] += v.x; pn[qc*4+1] += v.y; pn[qc*4+2] += v.z; pn[qc*4+3] += v.w;
            }
        }
        h2 pnp[8];
        #pragma unroll
        for (int i = 0; i < 8; ++i) pnp[i] = pk(pn[2 * i], pn[2 * i + 1]);
        float rp[8];
        #pragma unroll
        for (int r = 0; r < 8; ++r) rp[r] = 0.f;
        #pragma unroll
        for (int i = 0; i < 8; ++i) {   // f-pairs in this wave's slice
            float t0 = rnb1[fb + 2 * i], t1 = rnb1[fb + 2 * i + 1];
            #pragma unroll
            for (int p = 0; p < 8; ++p) {
                t0 = dot2(pnp[p], u2h(wsu[OFF_RNW1 + p * 64 + fb + 2 * i]), t0);
                t1 = dot2(pnp[p], u2h(wsu[OFF_RNW1 + p * 64 + fb + 2 * i + 1]), t1);
            }
            const h2 tp = pk(fmaxf(t0, 0.f), fmaxf(t1, 0.f));
            #pragma unroll
            for (int r = 0; r < 8; ++r)
                rp[r] = dot2(tp, u2h(wsu[OFF_RNW2 + (8 * w + i) * 8 + r]), rp[r]);
        }
        bufB[w * 2 + 0][l] = make_float4(rp[0], rp[1], rp[2], rp[3]);
        bufB[w * 2 + 1][l] = make_float4(rp[4], rp[5], rp[6], rp[7]);
    }
    // stage obstacle block cols [69,133)
    #pragma unroll
    for (int it = 0; it < 8; ++it) {
        const int idx = it * 256 + tid;
        const int ee  = idx >> 5;
        const int cp  = idx & 31;
        const float* p = src + (size_t)ee * XCOLS + 69 + 2 * cp;
        xs_h[XS(cp, ee)] = h2u(pk(p[0], p[1]));
    }
    __syncthreads();  // B3

    // ================= Phase 3: rn full; obstacle L1 slice + po partial ========
    float rn[8];
    #pragma unroll
    for (int rc = 0; rc < 2; ++rc) {
        const float4 a = bufB[0 * 2 + rc][l];
        const float4 b = bufB[1 * 2 + rc][l];
        const float4 c4 = bufB[2 * 2 + rc][l];
        const float4 d = bufB[3 * 2 + rc][l];
        rn[rc*4+0] = a.x + b.x + c4.x + d.x + rnb2[rc*4+0];
        rn[rc*4+1] = a.y + b.y + c4.y + d.y + rnb2[rc*4+1];
        rn[rc*4+2] = a.z + b.z + c4.z + d.z + rnb2[rc*4+2];
        rn[rc*4+3] = a.w + b.w + c4.w + d.w + rnb2[rc*4+3];
    }
    {
        float so[16];
        #pragma unroll
        for (int f = 0; f < 16; ++f) so[f] = 0.f;
        for (int j = 0; j < NO; ++j) {
            const h2 hp2 = u2h(xs_h[XS(j, l)]);
            #pragma unroll
            for (int f = 0; f < 16; ++f) {
                const float t = dot2(hp2, u2h(wsu[OFF_POW1 + fb + f]), pob1[fb + f]);
                so[f] += fmaxf(t, 0.f);
            }
        }
        // obstacle barrier partials: wave handles j in [8w,8w+8)
        #pragma unroll
        for (int jj = 0; jj < 8; ++jj) {
            const int j = 8 * w + jj;
            const h2 hp2 = u2h(xs_h[XS(j, l)]);
            const float v0 = (float)hp2[0], v1 = (float)hp2[1];
            const float nrm = sqrtf(v0 * v0 + v1 * v1);
            const float cc  = 0.01f * __builtin_amdgcn_rcpf(nrm * (nrm - 0.5f));
            bar0 -= cc * v0;
            bar1 -= cc * v1;
        }
        h2 sop[8];
        #pragma unroll
        for (int i = 0; i < 8; ++i) sop[i] = pk(so[2 * i], so[2 * i + 1]);
        float po[16];
        #pragma unroll
        for (int q = 0; q < 16; ++q) po[q] = 0.f;
        #pragma unroll
        for (int p = 0; p < 8; ++p) {
            #pragma unroll
            for (int q = 0; q < 16; ++q)
                po[q] = dot2(sop[p], u2h(wsu[OFF_POW2 + (8 * w + p) * 16 + q]), po[q]);
        }
        #pragma unroll
        for (int qc = 0; qc < 4; ++qc)
            bufA[w * 4 + qc][l] = make_float4(po[qc*4+0], po[qc*4+1], po[qc*4+2], po[qc*4+3]);
    }
    __syncthreads();  // B4

    // ================= Phase 4: ro partial =====================================
    {
        float po[16];
        #pragma unroll
        for (int q = 0; q < 16; ++q) po[q] = 32.f * pob2[q];
        #pragma unroll
        for (int w2 = 0; w2 < 4; ++w2) {
            #pragma unroll
            for (int qc = 0; qc < 4; ++qc) {
                const float4 v = bufA[w2 * 4 + qc][l];
                po[qc*4+0] += v.x; po[qc*4+1] += v.y; po[qc*4+2] += v.z; po[qc*4+3] += v.w;
            }
        }
        h2 pop[8];
        #pragma unroll
        for (int i = 0; i < 8; ++i) pop[i] = pk(po[2 * i], po[2 * i + 1]);
        float op[8];
        #pragma unroll
        for (int r = 0; r < 8; ++r) op[r] = 0.f;
        #pragma unroll
        for (int i = 0; i < 8; ++i) {
            float t0 = rob1[fb + 2 * i], t1 = rob1[fb + 2 * i + 1];
            #pragma unroll
            for (int p = 0; p < 8; ++p) {
                t0 = dot2(pop[p], u2h(wsu[OFF_ROW1 + p * 64 + fb + 2 * i]), t0);
                t1 = dot2(pop[p], u2h(wsu[OFF_ROW1 + p * 64 + fb + 2 * i + 1]), t1);
            }
            const h2 tp = pk(fmaxf(t0, 0.f), fmaxf(t1, 0.f));
            #pragma unroll
            for (int r = 0; r < 8; ++r)
                op[r] = dot2(tp, u2h(wsu[OFF_ROW2 + (8 * w + i) * 8 + r]), op[r]);
        }
        bufB[w * 2 + 0][l] = make_float4(op[0], op[1], op[2], op[3]);
        bufB[w * 2 + 1][l] = make_float4(op[4], op[5], op[6], op[7]);
    }
    __syncthreads();  // B5

    // ================= Phase 5: ro full; psi L1 slice ==========================
    {
        float ro[8];
        #pragma unroll
        for (int rc = 0; rc < 2; ++rc) {
            const float4 a = bufB[0 * 2 + rc][l];
            const float4 b = bufB[1 * 2 + rc][l];
            const float4 c4 = bufB[2 * 2 + rc][l];
            const float4 d = bufB[3 * 2 + rc][l];
            ro[rc*4+0] = a.x + b.x + c4.x + d.x + rob2[rc*4+0];
            ro[rc*4+1] = a.y + b.y + c4.y + d.y + rob2[rc*4+1];
            ro[rc*4+2] = a.z + b.z + c4.z + d.z + rob2[rc*4+2];
            ro[rc*4+3] = a.w + b.w + c4.w + d.w + rob2[rc*4+3];
        }
        h2 hp[9];
        #pragma unroll
        for (int i = 0; i < 4; ++i) hp[i] = pk(rn[2 * i], rn[2 * i + 1]);
        #pragma unroll
        for (int i = 0; i < 4; ++i) hp[4 + i] = pk(ro[2 * i], ro[2 * i + 1]);
        hp[8] = pk(g0, g1);
        float ha[16];
        #pragma unroll
        for (int f = 0; f < 16; ++f) {
            float t = psb1[fb + f];
            #pragma unroll
            for (int p = 0; p < 9; ++p)
                t = dot2(hp[p], u2h(wsu[OFF_PSW1 + p * 64 + fb + f]), t);
            ha[f] = fmaxf(t, 0.f);
        }
        #pragma unroll
        for (int c = 0; c < 4; ++c)
            bufA[w * 4 + c][l] = make_float4(ha[c*4+0], ha[c*4+1], ha[c*4+2], ha[c*4+3]);
    }
    __syncthreads();  // B6

    // ================= Phase 6: psi L2 slice + L3 partials =====================
    {
        float t2[16];
        #pragma unroll
        for (int f2 = 0; f2 < 16; ++f2) t2[f2] = psb2[fb + f2];
        for (int c = 0; c < 16; ++c) {
            const float4 hv = bufA[c][l];
            const h2 hA = pk(hv.x, hv.y);
            const h2 hB = pk(hv.z, hv.w);
            #pragma unroll
            for (int f2 = 0; f2 < 16; ++f2) {
                float t = t2[f2];
                t = dot2(hA, u2h(wsu[OFF_PSW2 + (2 * c) * 64 + fb + f2]), t);
                t = dot2(hB, u2h(wsu[OFF_PSW2 + (2 * c + 1) * 64 + fb + f2]), t);
                t2[f2] = t;
            }
        }
        float o0p = 0.f, o1p = 0.f;
        #pragma unroll
        for (int i = 0; i < 8; ++i) {
            const h2 tp = pk(fmaxf(t2[2 * i], 0.f), fmaxf(t2[2 * i + 1], 0.f));
            o0p = dot2(tp, u2h(wsu[OFF_PSW3 + (8 * w + i) * 2 + 0]), o0p);
            o1p = dot2(tp, u2h(wsu[OFF_PSW3 + (8 * w + i) * 2 + 1]), o1p);
        }
        bufB[w][l] = make_float4(o0p, o1p, bar0, bar1);
    }
    __syncthreads();  // B7

    // ================= Phase 7: finale (128 threads, 2 tanh chains each) =======
    if (tid < 128) {
        const int elem = tid >> 1;
        const int oi   = tid & 1;
        const float4 a = bufB[0][elem];
        const float4 b = bufB[1][elem];
        const float4 c4 = bufB[2][elem];
        const float4 d = bufB[3][elem];
        const float o   = (oi ? a.y + b.y + c4.y + d.y : a.x + b.x + c4.x + d.x)
                          + (oi ? psb3[1] : psb3[0]);
        const float bar = (oi ? a.w + b.w + c4.w + d.w : a.z + b.z + c4.z + d.z);
        const float e_  = 2.f * tanhf(o);
        const float av  = tanhf(e_ + bar + noise[2 * (size_t)e0 + tid]);
        out[2 * (size_t)e0 + tid] = 2.f * av;
    }
}

extern "C" void kernel_launch(void* const* d_in, const int* in_sizes, int n_in,
                              void* d_out, int out_size, void* d_ws, size_t ws_size,
                              hipStream_t stream) {
    const float* x    = (const float*)d_in[0];
    const float* nz   = (const float*)d_in[1];
    const float* pnW1 = (const float*)d_in[2];
    const float* pnb1 = (const float*)d_in[3];
    const float* pnW2 = (const float*)d_in[4];
    const float* pnb2 = (const float*)d_in[5];
    const float* rnW1 = (const float*)d_in[6];
    const float* rnb1 = (const float*)d_in[7];
    const float* rnW2 = (const float*)d_in[8];
    const float* rnb2 = (const float*)d_in[9];
    const float* poW1 = (const float*)d_in[10];
    const float* pob1 = (const float*)d_in[11];
    const float* poW2 = (const float*)d_in[12];
    const float* pob2 = (const float*)d_in[13];
    const float* roW1 = (const float*)d_in[14];
    const float* rob1 = (const float*)d_in[15];
    const float* roW2 = (const float*)d_in[16];
    const float* rob2 = (const float*)d_in[17];
    const float* psW1 = (const float*)d_in[18];
    const float* psb1 = (const float*)d_in[19];
    const float* psW2 = (const float*)d_in[20];
    const float* psb2 = (const float*)d_in[21];
    const float* psW3 = (const float*)d_in[22];
    const float* psb3 = (const float*)d_in[23];

    unsigned* ws = (unsigned*)d_ws;
    hipLaunchKernelGGL(prep_weights, dim3(1), dim3(256), 0, stream,
        pnW1, pnW2, rnW1, rnW2, poW1, poW2, roW1, roW2, psW1, psW2, psW3, ws);

    const int b = in_sizes[0] / XCOLS;
    hipLaunchKernelGGL(barrier_net_kernel, dim3(b / 64), dim3(256), 0, stream,
        x, nz, pnb1, pnb2, rnb1, rnb2, pob1, pob2, rob1, rob2,
        psb1, psb2, psb3, ws, (float*)d_out);
}